// Round 1
// baseline (175.301 us; speedup 1.0000x reference)
//
#include <hip/hip_runtime.h>
#include <hip/hip_bf16.h>

// Problem constants (fixed by reference setup_inputs)
constexpr int B_ = 4, C_ = 256, H_ = 200, W_ = 336;
constexpr int OH_ = 7, OW_ = 7;
constexpr float SCALE_ = 0.25f;
constexpr int HW_ = H_ * W_;          // 67200
constexpr int OHW_ = OH_ * OW_;       // 49

// ---------------------------------------------------------------------------
// Kernel 1: transpose (B, C, H*W) -> (B, H*W, C) so channels are innermost.
// 32x32 tile in LDS, coalesced read along K (=H*W) and coalesced write along C.
// HW_ % 32 == 0 and C_ % 32 == 0, so no bounds checks needed.
// ---------------------------------------------------------------------------
__global__ __launch_bounds__(256) void transpose_bchw_bhwc(
    const float* __restrict__ in, float* __restrict__ out) {
  __shared__ float tile[32][33];  // +1 pad: conflict-free transposed read
  const int b  = blockIdx.z;
  const int k0 = blockIdx.x * 32;  // spatial (H*W) tile origin
  const int c0 = blockIdx.y * 32;  // channel tile origin
  const float* src = in  + (size_t)b * C_ * HW_;
  float*       dst = out + (size_t)b * HW_ * C_;
  const int tx = threadIdx.x;      // 0..31
  const int ty = threadIdx.y;      // 0..7

#pragma unroll
  for (int i = 0; i < 32; i += 8) {
    // read src[c0+ty+i][k0+tx]  (coalesced along k)
    tile[ty + i][tx] = src[(size_t)(c0 + ty + i) * HW_ + (k0 + tx)];
  }
  __syncthreads();
#pragma unroll
  for (int i = 0; i < 32; i += 8) {
    // write dst[k0+ty+i][c0+tx] (coalesced along c)
    dst[(size_t)(k0 + ty + i) * C_ + (c0 + tx)] = tile[tx][ty + i];
  }
}

// ---------------------------------------------------------------------------
// Kernel 2: RoIAlign gather from transposed features (B, H, W, C).
// One block per ROI, 256 threads = 256 channels. Per sample point the 4
// bilinear corner vectors are contiguous 1KB runs -> coalesced loads.
// Stage results in LDS laid out [c*49 + s] (odd stride -> no bank conflicts),
// then stream out linearly (fully coalesced stores).
// ---------------------------------------------------------------------------
__global__ __launch_bounds__(256) void roi_gather_T(
    const float* __restrict__ featT, const float* __restrict__ rois,
    const int* __restrict__ bidx, float* __restrict__ out) {
  __shared__ float vals[C_ * OHW_];  // 50176 B
  const int n = blockIdx.x;
  const int t = threadIdx.x;  // channel

  const float x1 = rois[n * 4 + 0] * SCALE_ - 0.5f;
  const float y1 = rois[n * 4 + 1] * SCALE_ - 0.5f;
  const float x2 = rois[n * 4 + 2] * SCALE_ - 0.5f;
  const float y2 = rois[n * 4 + 3] * SCALE_ - 0.5f;
  const float bw = (x2 - x1) * (1.0f / OW_);
  const float bh = (y2 - y1) * (1.0f / OH_);
  const int b = bidx[n];
  const float* fb = featT + (size_t)b * HW_ * C_;

#pragma unroll 4
  for (int s = 0; s < OHW_; ++s) {
    const int oh = s / OW_, ow = s % OW_;
    const float y = y1 + ((float)oh + 0.5f) * bh;
    const float x = x1 + ((float)ow + 0.5f) * bw;
    const bool valid =
        (y >= -1.0f) & (y <= (float)H_) & (x >= -1.0f) & (x <= (float)W_);
    const float yc = fminf(fmaxf(y, 0.0f), (float)(H_ - 1));
    const float xc = fminf(fmaxf(x, 0.0f), (float)(W_ - 1));
    const int yl = (int)yc;
    const int xl = (int)xc;
    const int yh = min(yl + 1, H_ - 1);
    const int xh = min(xl + 1, W_ - 1);
    const float ly = yc - (float)yl, lx = xc - (float)xl;
    const float hy = 1.0f - ly, hx = 1.0f - lx;

    const float* p00 = fb + ((size_t)yl * W_ + xl) * C_;
    const float* p01 = fb + ((size_t)yl * W_ + xh) * C_;
    const float* p10 = fb + ((size_t)yh * W_ + xl) * C_;
    const float* p11 = fb + ((size_t)yh * W_ + xh) * C_;

    float v = hy * hx * p00[t] + hy * lx * p01[t] +
              ly * hx * p10[t] + ly * lx * p11[t];
    vals[t * OHW_ + s] = valid ? v : 0.0f;
  }
  __syncthreads();

  float* po = out + (size_t)n * (C_ * OHW_);
#pragma unroll
  for (int k = 0; k < OHW_; ++k) {
    po[k * C_ + t] = vals[k * C_ + t];  // linear, coalesced
  }
}

// ---------------------------------------------------------------------------
// Fallback (only if ws too small): gather straight from (B, C, H, W).
// Uncoalesced but correct.
// ---------------------------------------------------------------------------
__global__ __launch_bounds__(256) void roi_gather_direct(
    const float* __restrict__ feat, const float* __restrict__ rois,
    const int* __restrict__ bidx, float* __restrict__ out) {
  __shared__ float vals[C_ * OHW_];
  const int n = blockIdx.x;
  const int t = threadIdx.x;

  const float x1 = rois[n * 4 + 0] * SCALE_ - 0.5f;
  const float y1 = rois[n * 4 + 1] * SCALE_ - 0.5f;
  const float x2 = rois[n * 4 + 2] * SCALE_ - 0.5f;
  const float y2 = rois[n * 4 + 3] * SCALE_ - 0.5f;
  const float bw = (x2 - x1) * (1.0f / OW_);
  const float bh = (y2 - y1) * (1.0f / OH_);
  const int b = bidx[n];
  const float* fc = feat + ((size_t)b * C_ + t) * HW_;

  for (int s = 0; s < OHW_; ++s) {
    const int oh = s / OW_, ow = s % OW_;
    const float y = y1 + ((float)oh + 0.5f) * bh;
    const float x = x1 + ((float)ow + 0.5f) * bw;
    const bool valid =
        (y >= -1.0f) & (y <= (float)H_) & (x >= -1.0f) & (x <= (float)W_);
    const float yc = fminf(fmaxf(y, 0.0f), (float)(H_ - 1));
    const float xc = fminf(fmaxf(x, 0.0f), (float)(W_ - 1));
    const int yl = (int)yc;
    const int xl = (int)xc;
    const int yh = min(yl + 1, H_ - 1);
    const int xh = min(xl + 1, W_ - 1);
    const float ly = yc - (float)yl, lx = xc - (float)xl;
    const float hy = 1.0f - ly, hx = 1.0f - lx;

    float v = hy * hx * fc[yl * W_ + xl] + hy * lx * fc[yl * W_ + xh] +
              ly * hx * fc[yh * W_ + xl] + ly * lx * fc[yh * W_ + xh];
    vals[t * OHW_ + s] = valid ? v : 0.0f;
  }
  __syncthreads();

  float* po = out + (size_t)n * (C_ * OHW_);
#pragma unroll
  for (int k = 0; k < OHW_; ++k) {
    po[k * C_ + t] = vals[k * C_ + t];
  }
}

extern "C" void kernel_launch(void* const* d_in, const int* in_sizes, int n_in,
                              void* d_out, int out_size, void* d_ws,
                              size_t ws_size, hipStream_t stream) {
  const float* feat = (const float*)d_in[0];
  const float* rois = (const float*)d_in[1];
  const int*   bidx = (const int*)d_in[2];
  float*       out  = (float*)d_out;
  const int nrois = in_sizes[1] / 4;

  const size_t need = (size_t)B_ * HW_ * C_ * sizeof(float);  // ~275 MB
  if (ws_size >= need) {
    float* featT = (float*)d_ws;
    dim3 tb(32, 8, 1);
    dim3 tg(HW_ / 32, C_ / 32, B_);  // (2100, 8, 4)
    transpose_bchw_bhwc<<<tg, tb, 0, stream>>>(feat, featT);
    roi_gather_T<<<nrois, 256, 0, stream>>>(featT, rois, bidx, out);
  } else {
    roi_gather_direct<<<nrois, 256, 0, stream>>>(feat, rois, bidx, out);
  }
}

// Round 2
// 140.570 us; speedup vs baseline: 1.2471x; 1.2471x over previous
//
#include <hip/hip_runtime.h>
#include <hip/hip_bf16.h>
#include <hip/hip_fp16.h>

// Problem constants (fixed by reference setup_inputs)
constexpr int B_ = 4, C_ = 256, H_ = 200, W_ = 336;
constexpr int OH_ = 7, OW_ = 7;
constexpr float SCALE_ = 0.25f;
constexpr int HW_ = H_ * W_;          // 67200
constexpr int OHW_ = OH_ * OW_;       // 49

// ---------------------------------------------------------------------------
// Kernel 1: transpose+downconvert (B, C, H*W) fp32 -> (B, H*W, C) fp16.
// featT is 137 MB -> fits in the 256 MB Infinity Cache, so the gather's
// corner reads become L3 hits instead of HBM traffic.
// 32x32 tile in LDS; coalesced read along K (=H*W), coalesced write along C.
// ---------------------------------------------------------------------------
__global__ __launch_bounds__(256) void transpose_bchw_bhwc_f16(
    const float* __restrict__ in, __half* __restrict__ out) {
  __shared__ float tile[32][33];  // +1 pad: conflict-free transposed read
  const int b  = blockIdx.z;
  const int k0 = blockIdx.x * 32;  // spatial (H*W) tile origin
  const int c0 = blockIdx.y * 32;  // channel tile origin
  const float* src = in  + (size_t)b * C_ * HW_;
  __half*      dst = out + (size_t)b * HW_ * C_;
  const int tx = threadIdx.x;      // 0..31
  const int ty = threadIdx.y;      // 0..7

#pragma unroll
  for (int i = 0; i < 32; i += 8) {
    tile[ty + i][tx] = src[(size_t)(c0 + ty + i) * HW_ + (k0 + tx)];
  }
  __syncthreads();
#pragma unroll
  for (int i = 0; i < 32; i += 8) {
    dst[(size_t)(k0 + ty + i) * C_ + (c0 + tx)] =
        __float2half(tile[tx][ty + i]);
  }
}

// ---------------------------------------------------------------------------
// Kernel 2: RoIAlign gather from fp16 (B, H, W, C) features.
// One block per ROI, 256 threads = 256 channels. Corner vectors are
// contiguous 512B runs -> coalesced, and L3-resident after kernel 1.
// Coordinate math hoisted into unrolled register arrays; 7x7 loop unrolled
// so the (L3-latency) loads pipeline. Results staged in LDS [c*49+s]
// (odd stride -> bank-conflict-free), then streamed out coalesced.
// ---------------------------------------------------------------------------
__global__ __launch_bounds__(256) void roi_gather_T_f16(
    const __half* __restrict__ featT, const float* __restrict__ rois,
    const int* __restrict__ bidx, float* __restrict__ out) {
  __shared__ float vals[C_ * OHW_];  // 50176 B -> 3 blocks/CU
  const int n = blockIdx.x;
  const int t = threadIdx.x;  // channel

  const float x1 = rois[n * 4 + 0] * SCALE_ - 0.5f;
  const float y1 = rois[n * 4 + 1] * SCALE_ - 0.5f;
  const float x2 = rois[n * 4 + 2] * SCALE_ - 0.5f;
  const float y2 = rois[n * 4 + 3] * SCALE_ - 0.5f;
  const float bw = (x2 - x1) * (1.0f / OW_);
  const float bh = (y2 - y1) * (1.0f / OH_);
  const int b = bidx[n];
  const __half* fb = featT + (size_t)b * HW_ * C_;

  // Hoisted per-axis sample math (static indexing -> registers).
  int   xli[OW_], xhi[OW_];
  float lxv[OW_];
  bool  vx[OW_];
#pragma unroll
  for (int ow = 0; ow < OW_; ++ow) {
    const float x = x1 + ((float)ow + 0.5f) * bw;
    vx[ow] = (x >= -1.0f) & (x <= (float)W_);
    const float xc = fminf(fmaxf(x, 0.0f), (float)(W_ - 1));
    const int xl = (int)xc;
    xli[ow] = xl;
    xhi[ow] = min(xl + 1, W_ - 1);
    lxv[ow] = xc - (float)xl;
  }
  int   yli[OH_], yhi[OH_];
  float lyv[OH_];
  bool  vy[OH_];
#pragma unroll
  for (int oh = 0; oh < OH_; ++oh) {
    const float y = y1 + ((float)oh + 0.5f) * bh;
    vy[oh] = (y >= -1.0f) & (y <= (float)H_);
    const float yc = fminf(fmaxf(y, 0.0f), (float)(H_ - 1));
    const int yl = (int)yc;
    yli[oh] = yl;
    yhi[oh] = min(yl + 1, H_ - 1);
    lyv[oh] = yc - (float)yl;
  }

#pragma unroll
  for (int oh = 0; oh < OH_; ++oh) {
    const __half* rl = fb + (size_t)yli[oh] * (W_ * C_);
    const __half* rh = fb + (size_t)yhi[oh] * (W_ * C_);
    const float ly = lyv[oh], hy = 1.0f - ly;
#pragma unroll
    for (int ow = 0; ow < OW_; ++ow) {
      const float lx = lxv[ow], hx = 1.0f - lx;
      const float v00 = __half2float(rl[xli[ow] * C_ + t]);
      const float v01 = __half2float(rl[xhi[ow] * C_ + t]);
      const float v10 = __half2float(rh[xli[ow] * C_ + t]);
      const float v11 = __half2float(rh[xhi[ow] * C_ + t]);
      float v = hy * (hx * v00 + lx * v01) + ly * (hx * v10 + lx * v11);
      vals[t * OHW_ + (oh * OW_ + ow)] = (vx[ow] & vy[oh]) ? v : 0.0f;
    }
  }
  __syncthreads();

  float* po = out + (size_t)n * (C_ * OHW_);
#pragma unroll
  for (int k = 0; k < OHW_; ++k) {
    po[k * C_ + t] = vals[k * C_ + t];  // linear, coalesced
  }
}

// ---------------------------------------------------------------------------
// Fallback (only if ws too small): gather straight from (B, C, H, W) fp32.
// Uncoalesced but correct.
// ---------------------------------------------------------------------------
__global__ __launch_bounds__(256) void roi_gather_direct(
    const float* __restrict__ feat, const float* __restrict__ rois,
    const int* __restrict__ bidx, float* __restrict__ out) {
  __shared__ float vals[C_ * OHW_];
  const int n = blockIdx.x;
  const int t = threadIdx.x;

  const float x1 = rois[n * 4 + 0] * SCALE_ - 0.5f;
  const float y1 = rois[n * 4 + 1] * SCALE_ - 0.5f;
  const float x2 = rois[n * 4 + 2] * SCALE_ - 0.5f;
  const float y2 = rois[n * 4 + 3] * SCALE_ - 0.5f;
  const float bw = (x2 - x1) * (1.0f / OW_);
  const float bh = (y2 - y1) * (1.0f / OH_);
  const int b = bidx[n];
  const float* fc = feat + ((size_t)b * C_ + t) * HW_;

  for (int s = 0; s < OHW_; ++s) {
    const int oh = s / OW_, ow = s % OW_;
    const float y = y1 + ((float)oh + 0.5f) * bh;
    const float x = x1 + ((float)ow + 0.5f) * bw;
    const bool valid =
        (y >= -1.0f) & (y <= (float)H_) & (x >= -1.0f) & (x <= (float)W_);
    const float yc = fminf(fmaxf(y, 0.0f), (float)(H_ - 1));
    const float xc = fminf(fmaxf(x, 0.0f), (float)(W_ - 1));
    const int yl = (int)yc;
    const int xl = (int)xc;
    const int yh = min(yl + 1, H_ - 1);
    const int xh = min(xl + 1, W_ - 1);
    const float ly = yc - (float)yl, lx = xc - (float)xl;
    const float hy = 1.0f - ly, hx = 1.0f - lx;

    float v = hy * hx * fc[yl * W_ + xl] + hy * lx * fc[yl * W_ + xh] +
              ly * hx * fc[yh * W_ + xl] + ly * lx * fc[yh * W_ + xh];
    vals[t * OHW_ + s] = valid ? v : 0.0f;
  }
  __syncthreads();

  float* po = out + (size_t)n * (C_ * OHW_);
#pragma unroll
  for (int k = 0; k < OHW_; ++k) {
    po[k * C_ + t] = vals[k * C_ + t];
  }
}

extern "C" void kernel_launch(void* const* d_in, const int* in_sizes, int n_in,
                              void* d_out, int out_size, void* d_ws,
                              size_t ws_size, hipStream_t stream) {
  const float* feat = (const float*)d_in[0];
  const float* rois = (const float*)d_in[1];
  const int*   bidx = (const int*)d_in[2];
  float*       out  = (float*)d_out;
  const int nrois = in_sizes[1] / 4;

  const size_t need = (size_t)B_ * HW_ * C_ * sizeof(__half);  // ~137 MB
  if (ws_size >= need) {
    __half* featT = (__half*)d_ws;
    dim3 tb(32, 8, 1);
    dim3 tg(HW_ / 32, C_ / 32, B_);  // (2100, 8, 4)
    transpose_bchw_bhwc_f16<<<tg, tb, 0, stream>>>(feat, featT);
    roi_gather_T_f16<<<nrois, 256, 0, stream>>>(featT, rois, bidx, out);
  } else {
    roi_gather_direct<<<nrois, 256, 0, stream>>>(feat, rois, bidx, out);
  }
}

// Round 3
// 116.603 us; speedup vs baseline: 1.5034x; 1.2055x over previous
//
#include <hip/hip_runtime.h>
#include <hip/hip_bf16.h>
#include <hip/hip_fp16.h>

// Problem constants (fixed by reference setup_inputs)
constexpr int B_ = 4, C_ = 256, H_ = 200, W_ = 336;
constexpr int OH_ = 7, OW_ = 7;
constexpr float SCALE_ = 0.25f;
constexpr int HW_ = H_ * W_;          // 67200
constexpr int OHW_ = OH_ * OW_;       // 49

typedef float f32x4 __attribute__((ext_vector_type(4)));

// ---------------------------------------------------------------------------
// Kernel 1: transpose+downconvert (B, C, H*W) fp32 -> (B, H*W, C) fp16.
// Tile = 64 channels x 32 spatial. Reads: 128B contiguous per wave-row,
// NON-TEMPORAL (feat is streamed once; don't let it evict featT from L3).
// Writes: lanes emit __half2 -> 128B contiguous per wave-row, temporal
// (featT should stay L3-resident for the gather).
// ---------------------------------------------------------------------------
__global__ __launch_bounds__(256) void transpose_bchw_bhwc_f16(
    const float* __restrict__ in, __half* __restrict__ out) {
  __shared__ float tile[64][33];  // [c'][k'], stride 33 -> <=2-way (free)
  const int b  = blockIdx.z;
  const int k0 = blockIdx.x * 32;  // spatial tile origin
  const int c0 = blockIdx.y * 64;  // channel tile origin
  const float* src = in + (size_t)b * C_ * HW_;
  __half2*     dst = (__half2*)(out + (size_t)b * HW_ * C_);
  const int tx = threadIdx.x & 31;
  const int ty = threadIdx.x >> 5;  // 0..7

#pragma unroll
  for (int p = 0; p < 8; ++p) {
    const int c = p * 8 + ty;
    tile[c][tx] = __builtin_nontemporal_load(
        &src[(size_t)(c0 + c) * HW_ + (k0 + tx)]);
  }
  __syncthreads();
#pragma unroll
  for (int q = 0; q < 4; ++q) {
    const int k = q * 8 + ty;
    const __half2 h = __halves2half2(__float2half(tile[2 * tx][k]),
                                     __float2half(tile[2 * tx + 1][k]));
    dst[(size_t)(k0 + k) * (C_ / 2) + (c0 / 2) + tx] = h;
  }
}

// ---------------------------------------------------------------------------
// Kernel 2: RoIAlign gather from fp16 (B, H, W, C) features.
// Per block (one ROI): threads 0..48 precompute the 49 samples' corner
// pixel offsets + bilinear weights (valid mask folded into weights) into
// LDS. Then 128 channel-pair lanes x 2 sample-phases loop the samples:
// 4 __half2 loads per sample (256B/wave/corner, L3-resident), FMA, stage
// results in LDS [c*49+s], stream out as nontemporal float4.
// ---------------------------------------------------------------------------
__global__ __launch_bounds__(256) void roi_gather_T_f16(
    const __half* __restrict__ featT, const float* __restrict__ rois,
    const int* __restrict__ bidx, float* __restrict__ out) {
  __shared__ float vals[C_ * OHW_];  // 50176 B
  __shared__ int   offs[4][OHW_];    // corner pixel index (y*W+x)
  __shared__ float wts[4][OHW_];     // bilinear weights, valid-folded
  const int n = blockIdx.x;
  const int t = threadIdx.x;

  if (t < OHW_) {
    const int s = t, oh = s / OW_, ow = s - oh * OW_;
    const float x1 = rois[n * 4 + 0] * SCALE_ - 0.5f;
    const float y1 = rois[n * 4 + 1] * SCALE_ - 0.5f;
    const float x2 = rois[n * 4 + 2] * SCALE_ - 0.5f;
    const float y2 = rois[n * 4 + 3] * SCALE_ - 0.5f;
    const float bw = (x2 - x1) * (1.0f / OW_);
    const float bh = (y2 - y1) * (1.0f / OH_);
    const float x = x1 + ((float)ow + 0.5f) * bw;
    const float y = y1 + ((float)oh + 0.5f) * bh;
    const bool valid =
        (y >= -1.0f) & (y <= (float)H_) & (x >= -1.0f) & (x <= (float)W_);
    const float xc = fminf(fmaxf(x, 0.0f), (float)(W_ - 1));
    const float yc = fminf(fmaxf(y, 0.0f), (float)(H_ - 1));
    const int xl = (int)xc, yl = (int)yc;
    const int xh = min(xl + 1, W_ - 1), yh = min(yl + 1, H_ - 1);
    const float lx = xc - (float)xl, ly = yc - (float)yl;
    const float hx = 1.0f - lx, hy = 1.0f - ly;
    const float vm = valid ? 1.0f : 0.0f;
    offs[0][s] = yl * W_ + xl;  wts[0][s] = vm * hy * hx;
    offs[1][s] = yl * W_ + xh;  wts[1][s] = vm * hy * lx;
    offs[2][s] = yh * W_ + xl;  wts[2][s] = vm * ly * hx;
    offs[3][s] = yh * W_ + xh;  wts[3][s] = vm * ly * lx;
  }
  __syncthreads();

  const int b = bidx[n];
  const __half2* fb2 = (const __half2*)(featT + (size_t)b * HW_ * C_);
  const int cp = t & 127;  // channel pair -> channels 2cp, 2cp+1
  const int sh = t >> 7;   // sample phase 0/1 (uniform per wave)

#pragma unroll 5
  for (int i = 0; i < 25; ++i) {
    const int s = 2 * i + sh;
    if (s < OHW_) {
      const float w0 = wts[0][s], w1 = wts[1][s];
      const float w2 = wts[2][s], w3 = wts[3][s];
      const __half2 a0 = fb2[(size_t)offs[0][s] * (C_ / 2) + cp];
      const __half2 a1 = fb2[(size_t)offs[1][s] * (C_ / 2) + cp];
      const __half2 a2 = fb2[(size_t)offs[2][s] * (C_ / 2) + cp];
      const __half2 a3 = fb2[(size_t)offs[3][s] * (C_ / 2) + cp];
      const float2 f0 = __half22float2(a0), f1 = __half22float2(a1);
      const float2 f2 = __half22float2(a2), f3 = __half22float2(a3);
      const float vlo = w0 * f0.x + w1 * f1.x + w2 * f2.x + w3 * f3.x;
      const float vhi = w0 * f0.y + w1 * f1.y + w2 * f2.y + w3 * f3.y;
      vals[(2 * cp)     * OHW_ + s] = vlo;
      vals[(2 * cp + 1) * OHW_ + s] = vhi;
    }
  }
  __syncthreads();

  // Stream out 12544 floats (= 3136 float4), nontemporal (never re-read;
  // keep it from evicting featT in L3).
  const f32x4* v4 = (const f32x4*)vals;
  float* po = out + (size_t)n * (C_ * OHW_);
#pragma unroll
  for (int p = 0; p < 13; ++p) {
    const int idx = p * 256 + t;
    if (idx < (C_ * OHW_) / 4) {
      __builtin_nontemporal_store(v4[idx], (f32x4*)&po[idx * 4]);
    }
  }
}

// ---------------------------------------------------------------------------
// Fallback (only if ws too small): gather straight from (B, C, H, W) fp32.
// Uncoalesced but correct.
// ---------------------------------------------------------------------------
__global__ __launch_bounds__(256) void roi_gather_direct(
    const float* __restrict__ feat, const float* __restrict__ rois,
    const int* __restrict__ bidx, float* __restrict__ out) {
  __shared__ float vals[C_ * OHW_];
  const int n = blockIdx.x;
  const int t = threadIdx.x;

  const float x1 = rois[n * 4 + 0] * SCALE_ - 0.5f;
  const float y1 = rois[n * 4 + 1] * SCALE_ - 0.5f;
  const float x2 = rois[n * 4 + 2] * SCALE_ - 0.5f;
  const float y2 = rois[n * 4 + 3] * SCALE_ - 0.5f;
  const float bw = (x2 - x1) * (1.0f / OW_);
  const float bh = (y2 - y1) * (1.0f / OH_);
  const int b = bidx[n];
  const float* fc = feat + ((size_t)b * C_ + t) * HW_;

  for (int s = 0; s < OHW_; ++s) {
    const int oh = s / OW_, ow = s % OW_;
    const float y = y1 + ((float)oh + 0.5f) * bh;
    const float x = x1 + ((float)ow + 0.5f) * bw;
    const bool valid =
        (y >= -1.0f) & (y <= (float)H_) & (x >= -1.0f) & (x <= (float)W_);
    const float yc = fminf(fmaxf(y, 0.0f), (float)(H_ - 1));
    const float xc = fminf(fmaxf(x, 0.0f), (float)(W_ - 1));
    const int yl = (int)yc;
    const int xl = (int)xc;
    const int yh = min(yl + 1, H_ - 1);
    const int xh = min(xl + 1, W_ - 1);
    const float ly = yc - (float)yl, lx = xc - (float)xl;
    const float hy = 1.0f - ly, hx = 1.0f - lx;

    float v = hy * hx * fc[yl * W_ + xl] + hy * lx * fc[yl * W_ + xh] +
              ly * hx * fc[yh * W_ + xl] + ly * lx * fc[yh * W_ + xh];
    vals[t * OHW_ + s] = valid ? v : 0.0f;
  }
  __syncthreads();

  float* po = out + (size_t)n * (C_ * OHW_);
#pragma unroll
  for (int k = 0; k < OHW_; ++k) {
    po[k * C_ + t] = vals[k * C_ + t];
  }
}

extern "C" void kernel_launch(void* const* d_in, const int* in_sizes, int n_in,
                              void* d_out, int out_size, void* d_ws,
                              size_t ws_size, hipStream_t stream) {
  const float* feat = (const float*)d_in[0];
  const float* rois = (const float*)d_in[1];
  const int*   bidx = (const int*)d_in[2];
  float*       out  = (float*)d_out;
  const int nrois = in_sizes[1] / 4;

  const size_t need = (size_t)B_ * HW_ * C_ * sizeof(__half);  // ~137 MB
  if (ws_size >= need) {
    __half* featT = (__half*)d_ws;
    dim3 tg(HW_ / 32, C_ / 64, B_);  // (2100, 4, 4)
    transpose_bchw_bhwc_f16<<<tg, 256, 0, stream>>>(feat, featT);
    roi_gather_T_f16<<<nrois, 256, 0, stream>>>(featT, rois, bidx, out);
  } else {
    roi_gather_direct<<<nrois, 256, 0, stream>>>(feat, rois, bidx, out);
  }
}

// Round 6
// 111.564 us; speedup vs baseline: 1.5713x; 1.0452x over previous
//
#include <hip/hip_runtime.h>
#include <hip/hip_bf16.h>
#include <hip/hip_fp16.h>

// Problem constants (fixed by reference setup_inputs)
constexpr int B_ = 4, C_ = 256, H_ = 200, W_ = 336;
constexpr int OH_ = 7, OW_ = 7;
constexpr float SCALE_ = 0.25f;
constexpr int HW_ = H_ * W_;          // 67200
constexpr int OHW_ = OH_ * OW_;       // 49
constexpr int CH_ = 128;              // channels per gather block (C_/2)

typedef float f32x4 __attribute__((ext_vector_type(4)));

// ---------------------------------------------------------------------------
// Kernel 1: transpose+downconvert (B, C, H*W) fp32 -> (B, H*W, C) fp16.
// Tile = 128 channels x 32 spatial. Read side: scalar nontemporal loads
// (feat is streamed exactly once; keep it out of L3 so featT stays
// resident), fp16 conversion fused -> each thread packs a channel pair
// into a uint (__half2). Write side: uint4 stores -> 256B contiguous per
// 16-lane group.
// ---------------------------------------------------------------------------
__global__ __launch_bounds__(256) void transpose_bchw_bhwc_f16(
    const float* __restrict__ in, __half* __restrict__ out) {
  __shared__ unsigned int tileu[32][68];  // [k][cu]; uint = 2 channels
  const int b  = blockIdx.z;
  const int k0 = blockIdx.x * 32;   // spatial tile origin
  const int c0 = blockIdx.y * 128;  // channel tile origin
  const float* src = in + (size_t)b * C_ * HW_;
  unsigned int* dst = (unsigned int*)(out + (size_t)b * HW_ * C_);

  const int tx = threadIdx.x & 31;  // k within tile
  const int rp = threadIdx.x >> 5;  // 0..7
#pragma unroll
  for (int i = 0; i < 8; ++i) {
    const int cu = rp * 8 + i;      // channel pair 0..63
    const float a = __builtin_nontemporal_load(
        &src[(size_t)(c0 + 2 * cu) * HW_ + k0 + tx]);
    const float c = __builtin_nontemporal_load(
        &src[(size_t)(c0 + 2 * cu + 1) * HW_ + k0 + tx]);
    const __half2 h = __halves2half2(__float2half(a), __float2half(c));
    tileu[tx][cu] = *(const unsigned int*)&h;
  }
  __syncthreads();

  const int q  = threadIdx.x & 15;  // uint4 index within k-row
  const int kk = threadIdx.x >> 4;  // 0..15
#pragma unroll
  for (int p = 0; p < 2; ++p) {
    const int k = kk + p * 16;
    const uint4 v = *(const uint4*)&tileu[k][4 * q];
    *(uint4*)&dst[(size_t)(k0 + k) * (C_ / 2) + (c0 / 2) + 4 * q] = v;
  }
}

// ---------------------------------------------------------------------------
// Kernel 2: RoIAlign gather from fp16 (B, H, W, C) features.
// Grid (nrois, 2): block handles one ROI x 128 channels. Threads 0..48
// precompute corner offsets + valid-folded bilinear weights into LDS.
// Compute: lane cp=0..63 owns local channel pair (2cp, 2cp+1); the 4
// waves each take samples s === wave (mod 4). 4 __half2 loads per sample
// (512B/wave/corner, L3-resident). Results staged in vals[c_local*49+s]
// (25 KB -> ~5 blocks/CU), then streamed out as linear nontemporal f32x4
// into out[n][c0+c][s] (output layout is (N, C, OH, OW): samples
// contiguous per channel -- this staging transpose is what R5 got wrong).
// ---------------------------------------------------------------------------
__global__ __launch_bounds__(256) void roi_gather_T_f16(
    const __half* __restrict__ featT, const float* __restrict__ rois,
    const int* __restrict__ bidx, float* __restrict__ out) {
  __shared__ float vals[CH_ * OHW_];  // 25088 B
  __shared__ int   offs[4][OHW_];     // corner pixel index (y*W+x)
  __shared__ float wts[4][OHW_];      // bilinear weights, valid-folded
  const int n   = blockIdx.x;
  const int ch0 = blockIdx.y * CH_;   // channel half origin (0 or 128)
  const int t   = threadIdx.x;

  if (t < OHW_) {
    const int s = t, oh = s / OW_, ow = s - oh * OW_;
    const float x1 = rois[n * 4 + 0] * SCALE_ - 0.5f;
    const float y1 = rois[n * 4 + 1] * SCALE_ - 0.5f;
    const float x2 = rois[n * 4 + 2] * SCALE_ - 0.5f;
    const float y2 = rois[n * 4 + 3] * SCALE_ - 0.5f;
    const float bw = (x2 - x1) * (1.0f / OW_);
    const float bh = (y2 - y1) * (1.0f / OH_);
    const float x = x1 + ((float)ow + 0.5f) * bw;
    const float y = y1 + ((float)oh + 0.5f) * bh;
    const bool valid =
        (y >= -1.0f) & (y <= (float)H_) & (x >= -1.0f) & (x <= (float)W_);
    const float xc = fminf(fmaxf(x, 0.0f), (float)(W_ - 1));
    const float yc = fminf(fmaxf(y, 0.0f), (float)(H_ - 1));
    const int xl = (int)xc, yl = (int)yc;
    const int xh = min(xl + 1, W_ - 1), yh = min(yl + 1, H_ - 1);
    const float lx = xc - (float)xl, ly = yc - (float)yl;
    const float hx = 1.0f - lx, hy = 1.0f - ly;
    const float vm = valid ? 1.0f : 0.0f;
    offs[0][s] = yl * W_ + xl;  wts[0][s] = vm * hy * hx;
    offs[1][s] = yl * W_ + xh;  wts[1][s] = vm * hy * lx;
    offs[2][s] = yh * W_ + xl;  wts[2][s] = vm * ly * hx;
    offs[3][s] = yh * W_ + xh;  wts[3][s] = vm * ly * lx;
  }
  __syncthreads();

  const int b = bidx[n];
  const __half2* fb2 =
      (const __half2*)(featT + (size_t)b * HW_ * C_) + (ch0 >> 1);
  const int cp = t & 63;   // local channel pair -> channels 2cp, 2cp+1
  const int sh = t >> 6;   // sample phase 0..3 (wave-uniform)

#pragma unroll 2
  for (int i = 0; i < 13; ++i) {
    const int s = 4 * i + sh;
    if (s < OHW_) {
      const float w0 = wts[0][s], w1 = wts[1][s];
      const float w2 = wts[2][s], w3 = wts[3][s];
      const __half2 a0 = fb2[(size_t)offs[0][s] * (C_ / 2) + cp];
      const __half2 a1 = fb2[(size_t)offs[1][s] * (C_ / 2) + cp];
      const __half2 a2 = fb2[(size_t)offs[2][s] * (C_ / 2) + cp];
      const __half2 a3 = fb2[(size_t)offs[3][s] * (C_ / 2) + cp];
      const float2 f0 = __half22float2(a0), f1 = __half22float2(a1);
      const float2 f2 = __half22float2(a2), f3 = __half22float2(a3);
      vals[(2 * cp)     * OHW_ + s] =
          w0 * f0.x + w1 * f1.x + w2 * f2.x + w3 * f3.x;
      vals[(2 * cp + 1) * OHW_ + s] =
          w0 * f0.y + w1 * f1.y + w2 * f2.y + w3 * f3.y;
    }
  }
  __syncthreads();

  // Stream out 6272 floats (= 1568 f32x4) -> out[n][ch0..ch0+127][s],
  // contiguous block, nontemporal (never re-read; protect featT in L3).
  const f32x4* v4 = (const f32x4*)vals;
  float* po = out + (size_t)n * (C_ * OHW_) + (size_t)ch0 * OHW_;
#pragma unroll
  for (int p = 0; p < 7; ++p) {
    const int idx = p * 256 + t;
    if (idx < (CH_ * OHW_) / 4) {
      __builtin_nontemporal_store(v4[idx], (f32x4*)&po[idx * 4]);
    }
  }
}

// ---------------------------------------------------------------------------
// Fallback (only if ws too small): gather straight from (B, C, H, W) fp32.
// Uncoalesced but correct.
// ---------------------------------------------------------------------------
__global__ __launch_bounds__(256) void roi_gather_direct(
    const float* __restrict__ feat, const float* __restrict__ rois,
    const int* __restrict__ bidx, float* __restrict__ out) {
  __shared__ float vals[C_ * OHW_];
  const int n = blockIdx.x;
  const int t = threadIdx.x;

  const float x1 = rois[n * 4 + 0] * SCALE_ - 0.5f;
  const float y1 = rois[n * 4 + 1] * SCALE_ - 0.5f;
  const float x2 = rois[n * 4 + 2] * SCALE_ - 0.5f;
  const float y2 = rois[n * 4 + 3] * SCALE_ - 0.5f;
  const float bw = (x2 - x1) * (1.0f / OW_);
  const float bh = (y2 - y1) * (1.0f / OH_);
  const int b = bidx[n];
  const float* fc = feat + ((size_t)b * C_ + t) * HW_;

  for (int s = 0; s < OHW_; ++s) {
    const int oh = s / OW_, ow = s % OW_;
    const float y = y1 + ((float)oh + 0.5f) * bh;
    const float x = x1 + ((float)ow + 0.5f) * bw;
    const bool valid =
        (y >= -1.0f) & (y <= (float)H_) & (x >= -1.0f) & (x <= (float)W_);
    const float yc = fminf(fmaxf(y, 0.0f), (float)(H_ - 1));
    const float xc = fminf(fmaxf(x, 0.0f), (float)(W_ - 1));
    const int yl = (int)yc;
    const int xl = (int)xc;
    const int yh = min(yl + 1, H_ - 1);
    const int xh = min(xl + 1, W_ - 1);
    const float ly = yc - (float)yl, lx = xc - (float)xl;
    const float hy = 1.0f - ly, hx = 1.0f - lx;

    float v = hy * hx * fc[yl * W_ + xl] + hy * lx * fc[yl * W_ + xh] +
              ly * hx * fc[yh * W_ + xl] + ly * lx * fc[yh * W_ + xh];
    vals[t * OHW_ + s] = valid ? v : 0.0f;
  }
  __syncthreads();

  float* po = out + (size_t)n * (C_ * OHW_);
#pragma unroll
  for (int k = 0; k < OHW_; ++k) {
    po[k * C_ + t] = vals[k * C_ + t];
  }
}

extern "C" void kernel_launch(void* const* d_in, const int* in_sizes, int n_in,
                              void* d_out, int out_size, void* d_ws,
                              size_t ws_size, hipStream_t stream) {
  const float* feat = (const float*)d_in[0];
  const float* rois = (const float*)d_in[1];
  const int*   bidx = (const int*)d_in[2];
  float*       out  = (float*)d_out;
  const int nrois = in_sizes[1] / 4;

  const size_t need = (size_t)B_ * HW_ * C_ * sizeof(__half);  // ~137 MB
  if (ws_size >= need) {
    __half* featT = (__half*)d_ws;
    dim3 tg(HW_ / 32, C_ / 128, B_);  // (2100, 2, 4)
    transpose_bchw_bhwc_f16<<<tg, 256, 0, stream>>>(feat, featT);
    dim3 gg(nrois, 2, 1);
    roi_gather_T_f16<<<gg, 256, 0, stream>>>(featT, rois, bidx, out);
  } else {
    roi_gather_direct<<<nrois, 256, 0, stream>>>(feat, rois, bidx, out);
  }
}